// Round 12
// baseline (363.469 us; speedup 1.0000x reference)
//
#include <hip/hip_runtime.h>
#include <math.h>

// NerfMLP, R12: pure-f16 weights (1-pass MFMA) x f16 activations.
// 2 rays/block (R6-R8 geometry, register-feasible now B halved):
// TPB=512, wave (m,n): m = ray (rows m*64..+63), n = col-quarter (64 cols,
// acc[4][4]). 2-deep rotating B prefetch (named sets, no dynamic indexing).
// LDS A-reads halve vs R11; per-ray fixed setup/render overhead halves.
// __launch_bounds__(512,2) -> VGPR cap 128 (only proven-good config).

#define SS 64
#define BB 4096
#define NB 2048   // 2 rays per block
#define NEAR_ 2.0f
#define FAR_ 6.0f
#define TPB 512
#define PLANE 477696  // f16 elems per plane in d_ws (lo plane unused)

typedef _Float16 v8h __attribute__((ext_vector_type(8)));
typedef float v4f __attribute__((ext_vector_type(4)));
typedef unsigned int u32x4 __attribute__((ext_vector_type(4)));

__device__ __constant__ const int kLoff[9] = {0, 8192, 73728, 139264, 204800,
                                              278528, 344064, 409600, 475136};

struct __align__(16) Smem {
  _Float16 h[128 * 256];    // 64 KB, swizzled f16 (2 rays: rows 0-63 / 64-127)
  _Float16 enc[128 * 32];   // 8 KB, swizzled (cols 30,31 zero)
  float dist[128];
  float vdir[2][3];
  float rgb[128][4];
};  // ~74.5 KB -> 2 blocks/CU (16 waves/CU)

__device__ __forceinline__ int hswz16(int row, int col) {
  return row * 256 + (((col >> 3) ^ (row & 7)) << 3) + (col & 7);
}
__device__ __forceinline__ int encswz16(int row, int col) {
  return row * 32 + (((col >> 3) ^ (row & 3)) << 3) + (col & 7);
}

__device__ __forceinline__ float dpp_swap1(float x) {
  // quad_perm [1,0,3,2]: lane <-> lane^1
  int yi = __builtin_amdgcn_mov_dpp(__builtin_bit_cast(int, x), 0xB1, 0xF, 0xF, true);
  return __builtin_bit_cast(float, yi);
}
__device__ __forceinline__ unsigned pack2(float lo, float hi) {
  const unsigned short a = __builtin_bit_cast(unsigned short, (_Float16)lo);
  const unsigned short b = __builtin_bit_cast(unsigned short, (_Float16)hi);
  return (unsigned)a | ((unsigned)b << 16);
}

// ---------------- prologue: weights -> fragment-ordered f16 hi/lo ----------
// (verbatim — verified layout; lo plane written but unused by main kernel)
struct WP { const float* p[9]; };

__launch_bounds__(TPB)
__global__ void prep_weights(WP wp, _Float16* __restrict__ ws) {
  const int starts[10] = {0, 1, 9, 17, 25, 34, 42, 50, 58, 63};
  __shared__ float wtmp[32 * 256];
  const int bi = blockIdx.x;
  int layer = 0;
  #pragma unroll
  for (int i = 1; i < 9; ++i) if (bi >= starts[i]) layer = i;
  const int kstep = bi - starts[layer];
  const int ntiles = (layer == 8) ? 1 : 16;
  const int ncols = ntiles * 16;
  const int tid = threadIdx.x;
  const float* __restrict__ W = wp.p[layer];

  for (int idx = tid; idx < 32 * ncols; idx += TPB) {
    const int k = idx / ncols;
    const int nn = idx % ncols;
    const int gk = kstep * 32 + k;
    float v = 0.f;
    switch (layer) {
      case 0: if (gk < 30) v = W[gk * 256 + nn]; break;
      case 4: if (gk < 286) v = W[gk * 256 + nn]; break;
      case 7: if (nn < 129) v = W[gk * 129 + nn]; break;
      case 8: if (gk >= 1 && gk <= 131 && nn < 3) v = W[(gk - 1) * 3 + nn]; break;
      default: v = W[gk * 256 + nn];
    }
    wtmp[k * 256 + nn] = v;
  }
  __syncthreads();

  const int nelems = ntiles * 512;
  const int base = kLoff[layer] + kstep * nelems;
  for (int e0 = tid * 16; e0 < nelems; e0 += TPB * 16) {
    _Float16 hbuf[16], lbuf[16];
    #pragma unroll
    for (int j16 = 0; j16 < 16; ++j16) {
      const int e = e0 + j16;
      const int tile = e >> 9;
      const int lanee = (e >> 3) & 63;
      const int j = e & 7;
      const int k = ((lanee >> 4) << 3) + j;
      const int nn = tile * 16 + (lanee & 15);
      const float v = wtmp[k * 256 + nn];
      const _Float16 hi = (_Float16)v;
      hbuf[j16] = hi;
      lbuf[j16] = (_Float16)(v - (float)hi);
    }
    *(u32x4*)(ws + base + e0)             = *(const u32x4*)&hbuf[0];
    *(u32x4*)(ws + base + e0 + 8)         = *(const u32x4*)&hbuf[8];
    *(u32x4*)(ws + PLANE + base + e0)     = *(const u32x4*)&lbuf[0];
    *(u32x4*)(ws + PLANE + base + e0 + 8) = *(const u32x4*)&lbuf[8];
  }
}

// ---------------- main-layer helpers ---------------------------------------
__device__ __forceinline__ void ldb4(const _Float16* __restrict__ gp, int s,
                                     v8h* b) {
  #pragma unroll
  for (int t = 0; t < 4; ++t)
    b[t] = *(const v8h*)(gp + s * 8192 + t * 512);
}
__device__ __forceinline__ void lda_h(const Smem& sm, int rbase, int s, int r,
                                      int g, v8h* a) {
  #pragma unroll
  for (int mt = 0; mt < 4; ++mt)
    a[mt] = *(const v8h*)&sm.h[hswz16(rbase + mt * 16 + r, s * 32 + g * 8)];
}
__device__ __forceinline__ void lda_e(const Smem& sm, int rbase, int r, int g,
                                      v8h* a) {
  #pragma unroll
  for (int mt = 0; mt < 4; ++mt)
    a[mt] = *(const v8h*)&sm.enc[encswz16(rbase + mt * 16 + r, g * 8)];
}
__device__ __forceinline__ void domfma4(const v8h* a, const v8h* b,
                                        v4f acc[4][4]) {
  #pragma unroll
  for (int t = 0; t < 4; ++t)
    #pragma unroll
    for (int mt = 0; mt < 4; ++mt)
      acc[mt][t] = __builtin_amdgcn_mfma_f32_16x16x32_f16(a[mt], b[t], acc[mt][t], 0, 0, 0);
}

// MODE: 0 = enc only (NS=1), 1 = h only (NS=8), 2 = h steps 0-7 + enc step 8
template <int MODE, int NREAL>
__device__ void run_layer(const _Float16* __restrict__ ws, int loff,
                          const float* __restrict__ Bv, Smem& sm) {
  const int tid = threadIdx.x;
  const int w = tid >> 6, lane = tid & 63;
  const int m = w >> 2, n = w & 3;       // m = ray half, n = col quarter
  const int rbase = m * 64;
  const int r = lane & 15, g = lane >> 4;
  v4f acc[4][4];
  #pragma unroll
  for (int mt = 0; mt < 4; ++mt)
    #pragma unroll
    for (int t = 0; t < 4; ++t) acc[mt][t] = (v4f){0.f, 0.f, 0.f, 0.f};

  const _Float16* gp = ws + loff + n * 2048 + lane * 8;
  v8h bA[4], bB[4], a[4];

  if (MODE == 0) {
    ldb4(gp, 0, bA);
    lda_e(sm, rbase, r, g, a);
    domfma4(a, bA, acc);
  } else {
    // 2-deep rotating prefetch: B[s] issued 2 substeps before use.
    ldb4(gp, 0, bA);
    ldb4(gp, 1, bB);
    lda_h(sm, rbase, 0, r, g, a); domfma4(a, bA, acc); ldb4(gp, 2, bA);
    lda_h(sm, rbase, 1, r, g, a); domfma4(a, bB, acc); ldb4(gp, 3, bB);
    lda_h(sm, rbase, 2, r, g, a); domfma4(a, bA, acc); ldb4(gp, 4, bA);
    lda_h(sm, rbase, 3, r, g, a); domfma4(a, bB, acc); ldb4(gp, 5, bB);
    lda_h(sm, rbase, 4, r, g, a); domfma4(a, bA, acc); ldb4(gp, 6, bA);
    lda_h(sm, rbase, 5, r, g, a); domfma4(a, bB, acc); ldb4(gp, 7, bB);
    lda_h(sm, rbase, 6, r, g, a); domfma4(a, bA, acc);
    if (MODE == 2) ldb4(gp, 8, bA);
    lda_h(sm, rbase, 7, r, g, a); domfma4(a, bB, acc);
    if (MODE == 2) {  // s=8 tail: enc A-source
      lda_e(sm, rbase, r, g, a);
      domfma4(a, bA, acc);
    }
  }
  __syncthreads();  // all reads of h done before overwrite

  // epilogue: bias + relu, pack col-pairs via DPP swap, b32 writes
  const int sel = r & 1;
  #pragma unroll
  for (int t = 0; t < 4; ++t) {
    const int col = (n * 4 + t) * 16 + r;
    const float bias = (col < NREAL) ? Bv[col] : 0.f;
    #pragma unroll
    for (int mt = 0; mt < 4; ++mt) {
      float vv[4], nb[4];
      #pragma unroll
      for (int q = 0; q < 4; ++q) {
        vv[q] = fmaxf(acc[mt][t][q] + bias, 0.f);
        nb[q] = dpp_swap1(vv[q]);
      }
      const float o0 = vv[sel * 2 + 0], o1 = vv[sel * 2 + 1];
      const float p0 = nb[sel * 2 + 0], p1 = nb[sel * 2 + 1];
      const unsigned w0 = sel ? pack2(p0, o0) : pack2(o0, p0);
      const unsigned w1 = sel ? pack2(p1, o1) : pack2(o1, p1);
      const int colp = col & ~1;
      const int row0 = rbase + mt * 16 + g * 4 + sel * 2;
      ((unsigned*)sm.h)[hswz16(row0, colp) >> 1] = w0;
      ((unsigned*)sm.h)[hswz16(row0 + 1, colp) >> 1] = w1;
    }
  }
  __syncthreads();
}

__launch_bounds__(TPB, 2)
__global__ void nerf_mfma(const float* __restrict__ x, const float* __restrict__ off,
                          const float* __restrict__ b0, const float* __restrict__ b1,
                          const float* __restrict__ b2, const float* __restrict__ b3,
                          const float* __restrict__ b4, const float* __restrict__ b5,
                          const float* __restrict__ b6, const float* __restrict__ b7,
                          const float* __restrict__ b8,
                          const _Float16* __restrict__ ws, float* __restrict__ out) {
  __shared__ Smem sm;
  const int tid = threadIdx.x;

  // ---- setup: 2 rays, one thread per sample (threads 0..127) ----
  if (tid < 128) {
    const int rayi = tid >> 6;
    const int s = tid & 63;
    const int row = tid;                       // ray0: 0-63, ray1: 64-127
    const int b2 = blockIdx.x * 2 + rayi;
    const float ox = x[b2 * 6 + 0], oy = x[b2 * 6 + 1], oz = x[b2 * 6 + 2];
    const float dx = x[b2 * 6 + 3], dy = x[b2 * 6 + 4], dz = x[b2 * 6 + 5];
    const float norm = sqrtf(dx * dx + dy * dy + dz * dz);
    if (s == 0) {
      sm.vdir[rayi][0] = dx / norm;
      sm.vdir[rayi][1] = dy / norm;
      sm.vdir[rayi][2] = dz / norm;
    }
    const float offv = off[s * BB + b2];
    const float z = NEAR_ + (s + offv) * ((FAR_ - NEAR_) / SS);
    float dist;
    if (s < SS - 1) {
      const float offn = off[(s + 1) * BB + b2];
      const float zn = NEAR_ + (s + 1 + offn) * ((FAR_ - NEAR_) / SS);
      dist = (zn - z) * norm;
    } else {
      dist = 1e10f;
    }
    sm.dist[row] = dist;
    const float pos[3] = {ox + dx * z, oy + dy * z, oz + dz * z};
    #pragma unroll
    for (int c = 0; c < 3; ++c) {
      #pragma unroll
      for (int l = 0; l < 5; ++l) {
        const float freq = (float)M_PI * exp2f((float)(l - 2));
        float sv, cv;
        sincosf(pos[c] * freq, &sv, &cv);
        sm.enc[encswz16(row, c * 10 + l * 2 + 0)] = (_Float16)sv;
        sm.enc[encswz16(row, c * 10 + l * 2 + 1)] = (_Float16)cv;
      }
    }
    sm.enc[encswz16(row, 30)] = (_Float16)0.f;
    sm.enc[encswz16(row, 31)] = (_Float16)0.f;
  }
  __syncthreads();

  run_layer<0, 256>(ws, 0,      b0, sm);
  run_layer<1, 256>(ws, 8192,   b1, sm);
  run_layer<1, 256>(ws, 73728,  b2, sm);
  run_layer<1, 256>(ws, 139264, b3, sm);
  run_layer<2, 256>(ws, 204800, b4, sm);
  run_layer<1, 256>(ws, 278528, b5, sm);
  run_layer<1, 256>(ws, 344064, b6, sm);
  run_layer<1, 129>(ws, 409600, b7, sm);  // fd: [relu(density), relu(feat), 0]

  // overwrite cols 129..131 with raw viewdir (per ray)
  if (tid < 128) {
    const int rayi = tid >> 6;
    #pragma unroll
    for (int c = 0; c < 3; ++c)
      sm.h[hswz16(tid, 129 + c)] = (_Float16)sm.vdir[rayi][c];
  }
  __syncthreads();

  // color head: K=160 (w8 frag rows 0 and >=132 zeroed in prologue).
  // 8 waves, one 16-row M-tile each (128 rows); B from global, 1-pass.
  const int w = tid >> 6, lane = tid & 63;
  {
    const int r = lane & 15, g = lane >> 4;
    v4f hacc = (v4f){0.f, 0.f, 0.f, 0.f};
    #pragma unroll
    for (int s = 0; s < 5; ++s) {
      const int row = w * 16 + r;
      const v8h a = *(const v8h*)&sm.h[hswz16(row, s * 32 + g * 8)];
      const v8h bh = *(const v8h*)(ws + 475136 + s * 512 + lane * 8);
      hacc = __builtin_amdgcn_mfma_f32_16x16x32_f16(a, bh, hacc, 0, 0, 0);
    }
    if (r < 3) {
      const float bias = b8[r];
      #pragma unroll
      for (int q = 0; q < 4; ++q) {
        const int row = w * 16 + g * 4 + q;
        const float logit = hacc[q] + bias;
        sm.rgb[row][r] = 1.f / (1.f + expf(-logit));
      }
    }
  }
  __syncthreads();

  // volume render: wave 0 -> ray0, wave 1 -> ray1 (one lane per sample)
  if (w < 2) {
    const int p = lane;
    const int row = w * 64 + p;
    const float dens = (float)sm.h[hswz16(row, 0)];
    const float alpha = 1.f - expf(-fmaxf(dens, 0.f) * sm.dist[row]);
    float cum = 1.f - alpha + 1e-10f;
    #pragma unroll
    for (int d = 1; d < 64; d <<= 1) {
      const float up = __shfl_up(cum, d, 64);
      if (p >= d) cum *= up;
    }
    const float wgt = alpha * cum;
    float oc[3] = {sm.rgb[row][0] * wgt, sm.rgb[row][1] * wgt, sm.rgb[row][2] * wgt};
    #pragma unroll
    for (int d = 32; d >= 1; d >>= 1) {
      #pragma unroll
      for (int c = 0; c < 3; ++c) oc[c] += __shfl_down(oc[c], d, 64);
    }
    if (p == 0) {
      const int b2 = blockIdx.x * 2 + w;
      out[b2 * 3 + 0] = oc[0];
      out[b2 * 3 + 1] = oc[1];
      out[b2 * 3 + 2] = oc[2];
    }
  }
}

extern "C" void kernel_launch(void* const* d_in, const int* in_sizes, int n_in,
                              void* d_out, int out_size, void* d_ws, size_t ws_size,
                              hipStream_t stream) {
  (void)in_sizes; (void)n_in; (void)out_size; (void)ws_size;
  const float* x   = (const float*)d_in[0];
  const float* off = (const float*)d_in[1];
  WP wp;
  wp.p[0] = (const float*)d_in[2];
  wp.p[1] = (const float*)d_in[4];
  wp.p[2] = (const float*)d_in[6];
  wp.p[3] = (const float*)d_in[8];
  wp.p[4] = (const float*)d_in[10];
  wp.p[5] = (const float*)d_in[12];
  wp.p[6] = (const float*)d_in[14];
  wp.p[7] = (const float*)d_in[16];
  wp.p[8] = (const float*)d_in[18];
  const float* b0 = (const float*)d_in[3];
  const float* b1 = (const float*)d_in[5];
  const float* b2 = (const float*)d_in[7];
  const float* b3 = (const float*)d_in[9];
  const float* b4 = (const float*)d_in[11];
  const float* b5 = (const float*)d_in[13];
  const float* b6 = (const float*)d_in[15];
  const float* b7 = (const float*)d_in[17];
  const float* b8 = (const float*)d_in[19];
  _Float16* ws = (_Float16*)d_ws;

  prep_weights<<<63, TPB, 0, stream>>>(wp, ws);
  nerf_mfma<<<NB, TPB, 0, stream>>>(x, off, b0, b1, b2, b3, b4, b5, b6, b7, b8,
                                    ws, (float*)d_out);
}

// Round 13
// 295.806 us; speedup vs baseline: 1.2287x; 1.2287x over previous
//
#include <hip/hip_runtime.h>
#include <math.h>

// NerfMLP, R13: R11 structure (pure-f16 weights, 1-pass MFMA, 1 ray/block,
// TPB=512, 8 waves, wave n owns cols n*32..+31, 4-deep rotating B prefetch,
// VGPR<=64 -> 8 waves/SIMD, 4 blocks/CU = 32 waves) with overhead trims:
// enc setup spread across all 512 threads (__sincosf), dist via shfl,
// __expf in head/render, prep skips unused lo-plane.
// R12 lesson: never exceed 64 VGPR here - occupancy halves and loses 18%.

#define SS 64
#define BB 4096
#define NEAR_ 2.0f
#define FAR_ 6.0f
#define TPB 512
#define PLANE 477696  // f16 elems per plane in d_ws (layout kept; lo unused)

typedef _Float16 v8h __attribute__((ext_vector_type(8)));
typedef float v4f __attribute__((ext_vector_type(4)));
typedef unsigned int u32x4 __attribute__((ext_vector_type(4)));

__device__ __constant__ const int kLoff[9] = {0, 8192, 73728, 139264, 204800,
                                              278528, 344064, 409600, 475136};

struct __align__(16) Smem {
  _Float16 h[64 * 256];    // 32 KB, swizzled f16
  _Float16 enc[64 * 32];   // 4 KB, swizzled (cols 30,31 zero)
  float dist[64];
  float vdir[3];
  float rgb[64][4];
};  // ~37.3 KB -> 4 blocks/CU

__device__ __forceinline__ int hswz16(int row, int col) {
  return row * 256 + (((col >> 3) ^ (row & 7)) << 3) + (col & 7);
}
__device__ __forceinline__ int encswz16(int row, int col) {
  return row * 32 + (((col >> 3) ^ (row & 3)) << 3) + (col & 7);
}

__device__ __forceinline__ float dpp_swap1(float x) {
  int yi = __builtin_amdgcn_mov_dpp(__builtin_bit_cast(int, x), 0xB1, 0xF, 0xF, true);
  return __builtin_bit_cast(float, yi);
}
__device__ __forceinline__ unsigned pack2(float lo, float hi) {
  const unsigned short a = __builtin_bit_cast(unsigned short, (_Float16)lo);
  const unsigned short b = __builtin_bit_cast(unsigned short, (_Float16)hi);
  return (unsigned)a | ((unsigned)b << 16);
}

// ---------------- prologue: weights -> fragment-ordered f16 (hi only) ------
struct WP { const float* p[9]; };

__launch_bounds__(TPB)
__global__ void prep_weights(WP wp, _Float16* __restrict__ ws) {
  const int starts[10] = {0, 1, 9, 17, 25, 34, 42, 50, 58, 63};
  __shared__ float wtmp[32 * 256];
  const int bi = blockIdx.x;
  int layer = 0;
  #pragma unroll
  for (int i = 1; i < 9; ++i) if (bi >= starts[i]) layer = i;
  const int kstep = bi - starts[layer];
  const int ntiles = (layer == 8) ? 1 : 16;
  const int ncols = ntiles * 16;
  const int tid = threadIdx.x;
  const float* __restrict__ W = wp.p[layer];

  for (int idx = tid; idx < 32 * ncols; idx += TPB) {
    const int k = idx / ncols;
    const int nn = idx % ncols;
    const int gk = kstep * 32 + k;
    float v = 0.f;
    switch (layer) {
      case 0: if (gk < 30) v = W[gk * 256 + nn]; break;
      case 4: if (gk < 286) v = W[gk * 256 + nn]; break;
      case 7: if (nn < 129) v = W[gk * 129 + nn]; break;
      case 8: if (gk >= 1 && gk <= 131 && nn < 3) v = W[(gk - 1) * 3 + nn]; break;
      default: v = W[gk * 256 + nn];
    }
    wtmp[k * 256 + nn] = v;
  }
  __syncthreads();

  const int nelems = ntiles * 512;
  const int base = kLoff[layer] + kstep * nelems;
  for (int e0 = tid * 16; e0 < nelems; e0 += TPB * 16) {
    _Float16 hbuf[16];
    #pragma unroll
    for (int j16 = 0; j16 < 16; ++j16) {
      const int e = e0 + j16;
      const int tile = e >> 9;
      const int lanee = (e >> 3) & 63;
      const int j = e & 7;
      const int k = ((lanee >> 4) << 3) + j;
      const int nn = tile * 16 + (lanee & 15);
      hbuf[j16] = (_Float16)wtmp[k * 256 + nn];
    }
    *(u32x4*)(ws + base + e0)     = *(const u32x4*)&hbuf[0];
    *(u32x4*)(ws + base + e0 + 8) = *(const u32x4*)&hbuf[8];
  }
}

// ---------------- main-layer helpers ---------------------------------------
__device__ __forceinline__ void ldb1(const _Float16* __restrict__ gp, int s,
                                     v8h* b) {
  b[0] = *(const v8h*)(gp + s * 8192);
  b[1] = *(const v8h*)(gp + s * 8192 + 512);
}
__device__ __forceinline__ void lda_h(const Smem& sm, int s, int r, int g,
                                      v8h* a) {
  #pragma unroll
  for (int mt = 0; mt < 4; ++mt)
    a[mt] = *(const v8h*)&sm.h[hswz16(mt * 16 + r, s * 32 + g * 8)];
}
__device__ __forceinline__ void lda_e(const Smem& sm, int r, int g, v8h* a) {
  #pragma unroll
  for (int mt = 0; mt < 4; ++mt)
    a[mt] = *(const v8h*)&sm.enc[encswz16(mt * 16 + r, g * 8)];
}
__device__ __forceinline__ void domfma(const v8h* a, const v8h* b,
                                       v4f acc[4][2]) {
  #pragma unroll
  for (int t = 0; t < 2; ++t)
    #pragma unroll
    for (int mt = 0; mt < 4; ++mt)
      acc[mt][t] = __builtin_amdgcn_mfma_f32_16x16x32_f16(a[mt], b[t], acc[mt][t], 0, 0, 0);
}

// MODE: 0 = enc only (NS=1), 1 = h only (NS=8), 2 = h steps 0-7 + enc step 8
template <int MODE, int NREAL>
__device__ void run_layer(const _Float16* __restrict__ ws, int loff,
                          const float* __restrict__ Bv, Smem& sm) {
  const int tid = threadIdx.x;
  const int n = tid >> 6, lane = tid & 63;
  const int r = lane & 15, g = lane >> 4;
  v4f acc[4][2];
  #pragma unroll
  for (int mt = 0; mt < 4; ++mt)
    #pragma unroll
    for (int t = 0; t < 2; ++t) acc[mt][t] = (v4f){0.f, 0.f, 0.f, 0.f};

  const _Float16* gp = ws + loff + n * 1024 + lane * 8;
  v8h bA[2], bB[2], bC[2], bD[2], a[4];

  if (MODE == 0) {
    ldb1(gp, 0, bA);
    lda_e(sm, r, g, a);
    domfma(a, bA, acc);
  } else {
    // 4-deep rotating prefetch: B[s] issued 4 substeps before use.
    ldb1(gp, 0, bA);
    ldb1(gp, 1, bB);
    ldb1(gp, 2, bC);
    ldb1(gp, 3, bD);
    lda_h(sm, 0, r, g, a); domfma(a, bA, acc); ldb1(gp, 4, bA);
    lda_h(sm, 1, r, g, a); domfma(a, bB, acc); ldb1(gp, 5, bB);
    lda_h(sm, 2, r, g, a); domfma(a, bC, acc); ldb1(gp, 6, bC);
    lda_h(sm, 3, r, g, a); domfma(a, bD, acc); ldb1(gp, 7, bD);
    lda_h(sm, 4, r, g, a); domfma(a, bA, acc);
    if (MODE == 2) ldb1(gp, 8, bA);
    lda_h(sm, 5, r, g, a); domfma(a, bB, acc);
    lda_h(sm, 6, r, g, a); domfma(a, bC, acc);
    lda_h(sm, 7, r, g, a); domfma(a, bD, acc);
    if (MODE == 2) {  // s=8 tail: enc A-source
      lda_e(sm, r, g, a);
      domfma(a, bA, acc);
    }
  }
  __syncthreads();  // all reads of h done before overwrite

  // epilogue: bias + relu, pack col-pairs via DPP swap, b32 writes
  const int sel = r & 1;
  #pragma unroll
  for (int t = 0; t < 2; ++t) {
    const int col = (n * 2 + t) * 16 + r;
    const float bias = (col < NREAL) ? Bv[col] : 0.f;
    #pragma unroll
    for (int mt = 0; mt < 4; ++mt) {
      float vv[4], nb[4];
      #pragma unroll
      for (int q = 0; q < 4; ++q) {
        vv[q] = fmaxf(acc[mt][t][q] + bias, 0.f);
        nb[q] = dpp_swap1(vv[q]);
      }
      const float o0 = vv[sel * 2 + 0], o1 = vv[sel * 2 + 1];
      const float p0 = nb[sel * 2 + 0], p1 = nb[sel * 2 + 1];
      const unsigned w0 = sel ? pack2(p0, o0) : pack2(o0, p0);
      const unsigned w1 = sel ? pack2(p1, o1) : pack2(o1, p1);
      const int colp = col & ~1;
      const int row0 = mt * 16 + g * 4 + sel * 2;
      ((unsigned*)sm.h)[hswz16(row0, colp) >> 1] = w0;
      ((unsigned*)sm.h)[hswz16(row0 + 1, colp) >> 1] = w1;
    }
  }
  __syncthreads();
}

__launch_bounds__(TPB, 2)
__global__ void nerf_mfma(const float* __restrict__ x, const float* __restrict__ off,
                          const float* __restrict__ b0, const float* __restrict__ b1,
                          const float* __restrict__ b2, const float* __restrict__ b3,
                          const float* __restrict__ b4, const float* __restrict__ b5,
                          const float* __restrict__ b6, const float* __restrict__ b7,
                          const float* __restrict__ b8,
                          const _Float16* __restrict__ ws, float* __restrict__ out) {
  __shared__ Smem sm;
  const int tid = threadIdx.x;
  const int b = blockIdx.x;

  const float ox = x[b * 6 + 0], oy = x[b * 6 + 1], oz = x[b * 6 + 2];
  const float dx = x[b * 6 + 3], dy = x[b * 6 + 4], dz = x[b * 6 + 5];
  const float norm = sqrtf(dx * dx + dy * dy + dz * dz);

  // ---- setup: dist via shfl (wave 0), enc spread across all 512 threads ---
  if (tid < 64) {
    const int s = tid;
    const float offv = off[s * BB + b];
    const float z = NEAR_ + (s + offv) * ((FAR_ - NEAR_) / SS);
    const float zn = __shfl_down(z, 1, 64);
    sm.dist[s] = (s < SS - 1) ? (zn - z) * norm : 1e10f;
    if (s == 0) {
      sm.vdir[0] = dx / norm; sm.vdir[1] = dy / norm; sm.vdir[2] = dz / norm;
    }
    sm.enc[encswz16(s, 30)] = (_Float16)0.f;
    sm.enc[encswz16(s, 31)] = (_Float16)0.f;
  }
  // 960 sincos items (64 samples x 3 coords x 5 freqs), 2 per thread
  #pragma unroll
  for (int pp = 0; pp < 2; ++pp) {
    const int p = tid + pp * TPB;
    if (p < 960) {
      const int s = p / 15, j = p % 15;
      const int c = j / 5, l = j % 5;
      const float offv = off[s * BB + b];
      const float z = NEAR_ + (s + offv) * ((FAR_ - NEAR_) / SS);
      const float oc = (c == 0) ? ox : ((c == 1) ? oy : oz);
      const float dc = (c == 0) ? dx : ((c == 1) ? dy : dz);
      const float posc = oc + dc * z;
      const float freq = (float)M_PI * exp2f((float)(l - 2));
      float sv, cv;
      __sincosf(posc * freq, &sv, &cv);
      sm.enc[encswz16(s, c * 10 + l * 2 + 0)] = (_Float16)sv;
      sm.enc[encswz16(s, c * 10 + l * 2 + 1)] = (_Float16)cv;
    }
  }
  __syncthreads();

  run_layer<0, 256>(ws, 0,      b0, sm);
  run_layer<1, 256>(ws, 8192,   b1, sm);
  run_layer<1, 256>(ws, 73728,  b2, sm);
  run_layer<1, 256>(ws, 139264, b3, sm);
  run_layer<2, 256>(ws, 204800, b4, sm);
  run_layer<1, 256>(ws, 278528, b5, sm);
  run_layer<1, 256>(ws, 344064, b6, sm);
  run_layer<1, 129>(ws, 409600, b7, sm);  // fd: [relu(density), relu(feat), 0]

  // overwrite cols 129..131 with raw viewdir
  if (tid < 64) {
    #pragma unroll
    for (int c = 0; c < 3; ++c)
      sm.h[hswz16(tid, 129 + c)] = (_Float16)sm.vdir[c];
  }
  __syncthreads();

  // color head: K=160 (w8 frag rows 0 and >=132 zeroed in prologue).
  // Waves 0..3, one 16-row M-tile each; B from global, 1-pass.
  const int w = tid >> 6, lane = tid & 63;
  if (w < 4) {
    const int r = lane & 15, g = lane >> 4;
    v4f hacc = (v4f){0.f, 0.f, 0.f, 0.f};
    #pragma unroll
    for (int s = 0; s < 5; ++s) {
      const int row = w * 16 + r;
      const v8h a = *(const v8h*)&sm.h[hswz16(row, s * 32 + g * 8)];
      const v8h bh = *(const v8h*)(ws + 475136 + s * 512 + lane * 8);
      hacc = __builtin_amdgcn_mfma_f32_16x16x32_f16(a, bh, hacc, 0, 0, 0);
    }
    if (r < 3) {
      const float bias = b8[r];
      #pragma unroll
      for (int q = 0; q < 4; ++q) {
        const int row = w * 16 + g * 4 + q;
        const float logit = hacc[q] + bias;
        sm.rgb[row][r] = 1.f / (1.f + __expf(-logit));
      }
    }
  }
  __syncthreads();

  // volume render (wave 0, one lane per sample)
  if (tid < 64) {
    const int p = tid;
    const float dens = (float)sm.h[hswz16(p, 0)];
    const float alpha = 1.f - __expf(-fmaxf(dens, 0.f) * sm.dist[p]);
    float cum = 1.f - alpha + 1e-10f;
    #pragma unroll
    for (int d = 1; d < 64; d <<= 1) {
      const float up = __shfl_up(cum, d, 64);
      if (p >= d) cum *= up;
    }
    const float wgt = alpha * cum;
    float oc[3] = {sm.rgb[p][0] * wgt, sm.rgb[p][1] * wgt, sm.rgb[p][2] * wgt};
    #pragma unroll
    for (int d = 32; d >= 1; d >>= 1) {
      #pragma unroll
      for (int c = 0; c < 3; ++c) oc[c] += __shfl_down(oc[c], d, 64);
    }
    if (p == 0) {
      out[b * 3 + 0] = oc[0];
      out[b * 3 + 1] = oc[1];
      out[b * 3 + 2] = oc[2];
    }
  }
}

extern "C" void kernel_launch(void* const* d_in, const int* in_sizes, int n_in,
                              void* d_out, int out_size, void* d_ws, size_t ws_size,
                              hipStream_t stream) {
  (void)in_sizes; (void)n_in; (void)out_size; (void)ws_size;
  const float* x   = (const float*)d_in[0];
  const float* off = (const float*)d_in[1];
  WP wp;
  wp.p[0] = (const float*)d_in[2];
  wp.p[1] = (const float*)d_in[4];
  wp.p[2] = (const float*)d_in[6];
  wp.p[3] = (const float*)d_in[8];
  wp.p[4] = (const float*)d_in[10];
  wp.p[5] = (const float*)d_in[12];
  wp.p[6] = (const float*)d_in[14];
  wp.p[7] = (const float*)d_in[16];
  wp.p[8] = (const float*)d_in[18];
  const float* b0 = (const float*)d_in[3];
  const float* b1 = (const float*)d_in[5];
  const float* b2 = (const float*)d_in[7];
  const float* b3 = (const float*)d_in[9];
  const float* b4 = (const float*)d_in[11];
  const float* b5 = (const float*)d_in[13];
  const float* b6 = (const float*)d_in[15];
  const float* b7 = (const float*)d_in[17];
  const float* b8 = (const float*)d_in[19];
  _Float16* ws = (_Float16*)d_ws;

  prep_weights<<<63, TPB, 0, stream>>>(wp, ws);
  nerf_mfma<<<BB, TPB, 0, stream>>>(x, off, b0, b1, b2, b3, b4, b5, b6, b7, b8,
                                    ws, (float*)d_out);
}